// Round 11
// baseline (429.939 us; speedup 1.0000x reference)
//
#include <hip/hip_runtime.h>
#include <hip/hip_bf16.h>
#include <hip/hip_cooperative_groups.h>

namespace cg = cooperative_groups;

#define DD 32
#define S1CAP 256
#define PERCAP 128      // per-S1-node in-edge cap (in-degree ~Poisson(16))
#define E2CAP 1024
#define GRID 512
#define TPB 256

struct Params {
    const float* x;
    const int* ei;
    int E, N;
    const float *W1a, *b1a, *W2a, *b2a, *W1b, *b1b, *W2b, *b2b;
    const int *op1p, *op2p;
    char* ws;
    float* out;
};

__device__ __forceinline__ void s1_insert(int u, int* nidx, int* s1_list,
                                          int* cnt, unsigned char* need) {
    need[u] = 1;
    int old = atomicCAS(&nidx[u], 0, -1);
    if (old == 0) {
        int pos = atomicAdd(&cnt[0], 1);
        if (pos < S1CAP) { s1_list[pos] = u; nidx[u] = pos + 1; }
    }
}

// ---------- fused single-launch cooperative kernel ----------
// Phases: 0 zero-ws | 1 scan1 (S1+e2) | 2 scan2 (CSR-lite e1) | 3 scan3
// (gated degree) | 4 layer1 at S1 | 5 layer2 at op1/op2 + dots.
// All separated by grid.sync(); ~12 KB LDS, <=128 VGPR -> 512 blocks co-resident.
__global__ __launch_bounds__(TPB, 4)
void k_fused(Params P) {
    cg::grid_group grid = cg::this_grid();
    __shared__ float Wsh[2][DD][DD];
    __shared__ int   sidx[PERCAP];
    __shared__ float snrm[PERCAP];
    __shared__ float aggsh[DD];
    __shared__ int   prow[PERCAP];
    __shared__ int   pw[PERCAP];
    __shared__ float pnrm[PERCAP];
    __shared__ float agg2[2][2][DD];   // [w][st][dd]
    __shared__ float ysh[2][2][DD];    // [st][w][dd]

    // decode workspace (must match host fallback layout)
    char* p = P.ws;
    int* cnt   = (int*)p;            p += 64;
    int* e1cnt = (int*)p;            p += S1CAP * 4;
    int* deg   = (int*)p;            p += (size_t)P.N * 4;
    int* nidx  = (int*)p;            p += (size_t)P.N * 4;
    unsigned char* need = (unsigned char*)p;
    size_t needpad = ((size_t)P.N + 15) & ~(size_t)15;
    p += needpad;
    int* s1_list = (int*)p;          p += S1CAP * 4;
    int* e1buf   = (int*)p;          p += (size_t)S1CAP * PERCAP * 4;
    int* e2_src  = (int*)p;          p += E2CAP * 4;
    int* e2_w    = (int*)p;          p += E2CAP * 4;
    float* hA    = (float*)p;        p += (size_t)S1CAP * DD * 4;
    float* hB    = (float*)p;

    int t = threadIdx.x;
    int gtid = blockIdx.x * TPB + t;
    int nth = gridDim.x * TPB;
    int E = P.E;
    const int* eis = P.ei;                    // src column
    const int* eid = P.ei + (size_t)E;        // dst column
    int nchunk = E >> 2;
    int tail = nchunk << 2;

    // ---- phase 0: zero [cnt | e1cnt | deg | nidx | need] ----
    {
        size_t zn16 = (64 + S1CAP * 4 + (size_t)P.N * 8 + needpad) >> 4;
        int4 z = make_int4(0, 0, 0, 0);
        int4* zp = (int4*)P.ws;
        for (size_t j = gtid; j < zn16; j += nth) zp[j] = z;
    }
    grid.sync();

    int o1 = P.op1p[0], o2 = P.op2p[0];

    // ---- phase 1: find in-edges of op1/op2 (-> e2), sources -> S1 ----
    if (gtid == 0) {
        s1_insert(o1, nidx, s1_list, cnt, need);
        s1_insert(o2, nidx, s1_list, cnt, need);
    }
    for (int c = gtid; c < nchunk; c += nth) {
        int4 d4 = ((const int4*)eid)[c];
        int dv[4] = {d4.x, d4.y, d4.z, d4.w};
#pragma unroll
        for (int k = 0; k < 4; ++k) {
            int d = dv[k];
            if (d == o1 || d == o2) {
                int s = eis[c * 4 + k];
                s1_insert(s, nidx, s1_list, cnt, need);
                int q = atomicAdd(&cnt[2], 1);
                if (q < E2CAP) { e2_src[q] = s; e2_w[q] = (d == o2); }
            }
        }
    }
    for (int e = tail + gtid; e < E; e += nth) {
        int d = eid[e];
        if (d == o1 || d == o2) {
            int s = eis[e];
            s1_insert(s, nidx, s1_list, cnt, need);
            int q = atomicAdd(&cnt[2], 1);
            if (q < E2CAP) { e2_src[q] = s; e2_w[q] = (d == o2); }
        }
    }
    grid.sync();

    // ---- phase 2: bucket in-edges of S1 into CSR-lite slots ----
    for (int c = gtid; c < nchunk; c += nth) {
        int4 d4 = ((const int4*)eid)[c];
        int dv[4] = {d4.x, d4.y, d4.z, d4.w};
#pragma unroll
        for (int k = 0; k < 4; ++k) {
            int ix = nidx[dv[k]];
            if (ix > 0) {
                int s = eis[c * 4 + k];
                int slot = atomicAdd(&e1cnt[ix - 1], 1);
                if (slot < PERCAP) e1buf[(size_t)(ix - 1) * PERCAP + slot] = s;
                need[s] = 1;
            }
        }
    }
    for (int e = tail + gtid; e < E; e += nth) {
        int ix = nidx[eid[e]];
        if (ix > 0) {
            int s = eis[e];
            int slot = atomicAdd(&e1cnt[ix - 1], 1);
            if (slot < PERCAP) e1buf[(size_t)(ix - 1) * PERCAP + slot] = s;
            need[s] = 1;
        }
    }
    grid.sync();

    // ---- phase 3: in-degree ONLY for needed nodes (~600 of 100k) ----
    for (int c = gtid; c < nchunk; c += nth) {
        int4 d4 = ((const int4*)eid)[c];
        int dv[4] = {d4.x, d4.y, d4.z, d4.w};
#pragma unroll
        for (int k = 0; k < 4; ++k) { int d = dv[k]; if (need[d]) atomicAdd(&deg[d], 1); }
    }
    for (int e = tail + gtid; e < E; e += nth) {
        int d = eid[e]; if (need[d]) atomicAdd(&deg[d], 1);
    }
    grid.sync();

    int s1n = cnt[0] < S1CAP ? cnt[0] : S1CAP;

    // ---- phase 4: layer 1 (both stacks) at S1 nodes; block i = node i ----
    if (blockIdx.x < s1n) {
        int i = blockIdx.x;
        {
            float* w0 = &Wsh[0][0][0];
            float* w1 = &Wsh[1][0][0];
            for (int j = t; j < DD * DD; j += TPB) { w0[j] = P.W1a[j]; w1[j] = P.W1b[j]; }
        }
        int u = s1_list[i];
        float dis_u = rsqrtf((float)deg[u] + 1.0f);
        int ci = e1cnt[i]; if (ci > PERCAP) ci = PERCAP;
        for (int j = t; j < ci; j += TPB) {        // parallel prep (deg gathers)
            int s = e1buf[(size_t)i * PERCAP + j];
            sidx[j] = s;
            snrm[j] = rsqrtf((float)deg[s] + 1.0f) * dis_u;   // dis_u block-uniform
        }
        __syncthreads();
        if (t < 64) {
            int dd = t & 31;
            float agg = dis_u * dis_u * P.x[(size_t)u * DD + dd];   // self-loop
#pragma unroll 4
            for (int j = 0; j < ci; ++j)
                agg += snrm[j] * P.x[(size_t)sidx[j] * DD + dd];
            if (t < DD) aggsh[dd] = agg;
        }
        __syncthreads();
        if (t < 64) {
            int st = t >> 5, dd = t & 31;
            float y = st ? P.b1b[dd] : P.b1a[dd];
#pragma unroll
            for (int k = 0; k < DD; ++k) y += aggsh[k] * Wsh[st][k][dd];
            y = fmaxf(y, 0.f);                     // ReLU
            (st ? hB : hA)[(size_t)i * DD + dd] = y;
        }
    }
    grid.sync();

    // ---- phase 5: layer 2 at op1/op2 + final dots (block 0 only) ----
    if (blockIdx.x == 0) {
        {
            float* w0 = &Wsh[0][0][0];
            float* w1 = &Wsh[1][0][0];
            for (int j = t; j < DD * DD; j += TPB) { w0[j] = P.W2a[j]; w1[j] = P.W2b[j]; }
        }
        int st = (t >> 6) & 1, w = (t >> 5) & 1, dd = t & 31;
        int v = w ? o2 : o1;
        float dis_v = rsqrtf((float)deg[v] + 1.0f);
        const float* h = st ? hB : hA;
        float agg = 0.f;
        if (t < 128) {
            int rv = nidx[v] - 1; if (rv < 0) rv = 0;
            agg = dis_v * dis_v * h[(size_t)rv * DD + dd];   // self-loop
        }
        int c2 = cnt[2] < E2CAP ? cnt[2] : E2CAP;
        for (int j0 = 0; j0 < c2; j0 += PERCAP) {
            int jn = c2 - j0; if (jn > PERCAP) jn = PERCAP;
            __syncthreads();
            if (t < jn) {                    // parallel prep (nidx/deg gathers)
                int s = e2_src[j0 + t];
                prow[t] = nidx[s] - 1;
                pw[t]   = e2_w[j0 + t];
                pnrm[t] = rsqrtf((float)deg[s] + 1.0f);   // src factor ONLY (r7 bug)
            }
            __syncthreads();
            if (t < 128) {
#pragma unroll 4
                for (int j = 0; j < jn; ++j) {
                    if (pw[j] == w && prow[j] >= 0)
                        agg += (pnrm[j] * dis_v) * h[(size_t)prow[j] * DD + dd];
                }
            }
        }
        if (t < 128) agg2[w][st][dd] = agg;
        __syncthreads();
        if (t < 128) {
            float y = st ? P.b2b[dd] : P.b2a[dd];
#pragma unroll
            for (int k = 0; k < DD; ++k) y += agg2[w][st][k] * Wsh[st][k][dd];
            ysh[st][w][dd] = y;
        }
        __syncthreads();
        if (t < 2) {
            float sum = 0.f;
            for (int k = 0; k < DD; ++k) sum += ysh[t][0][k] * ysh[t][1][k];
            P.out[t] = sum;                 // f32: out[0]=l1, out[1]=l2
        }
    }
}

// ---------- fallback path (round-8 proven 5-kernel pipeline) ----------
__global__ void k_scan1(const int* __restrict__ ei, int E,
                        const int* __restrict__ op1p, const int* __restrict__ op2p,
                        int* __restrict__ nidx, int* __restrict__ s1_list,
                        int* __restrict__ e2_src, int* __restrict__ e2_w,
                        int* __restrict__ cnt, unsigned char* __restrict__ need) {
    int tid = blockIdx.x * blockDim.x + threadIdx.x;
    int o1 = op1p[0], o2 = op2p[0];
    if (tid == 0) {
        s1_insert(o1, nidx, s1_list, cnt, need);
        s1_insert(o2, nidx, s1_list, cnt, need);
    }
    int base = tid * 4;
    if (base >= E) return;
    int end = base + 4; if (end > E) end = E;
    for (int e = base; e < end; ++e) {
        int d = ei[(size_t)E + e];
        if (d == o1 || d == o2) {
            int s = ei[e];
            s1_insert(s, nidx, s1_list, cnt, need);
            int p = atomicAdd(&cnt[2], 1);
            if (p < E2CAP) { e2_src[p] = s; e2_w[p] = (d == o2); }
        }
    }
}

__global__ void k_scan2(const int* __restrict__ ei, int E,
                        const int* __restrict__ nidx,
                        int* __restrict__ e1cnt, int* __restrict__ e1buf,
                        unsigned char* __restrict__ need) {
    int tid = blockIdx.x * blockDim.x + threadIdx.x;
    int base = tid * 4;
    if (base >= E) return;
    int end = base + 4; if (end > E) end = E;
    for (int e = base; e < end; ++e) {
        int ix = nidx[ei[(size_t)E + e]];
        if (ix > 0) {
            int s = ei[e];
            int slot = atomicAdd(&e1cnt[ix - 1], 1);
            if (slot < PERCAP) e1buf[(size_t)(ix - 1) * PERCAP + slot] = s;
            need[s] = 1;
        }
    }
}

__global__ void k_scan3(const int* __restrict__ ei, int E,
                        const unsigned char* __restrict__ need,
                        int* __restrict__ deg) {
    int tid = blockIdx.x * blockDim.x + threadIdx.x;
    int base = tid * 4;
    if (base >= E) return;
    int end = base + 4; if (end > E) end = E;
    for (int e = base; e < end; ++e) {
        int d = ei[(size_t)E + e]; if (need[d]) atomicAdd(&deg[d], 1);
    }
}

__global__ __launch_bounds__(64)
void k_layer1(const float* __restrict__ x, const int* __restrict__ deg,
              const float* __restrict__ W1a, const float* __restrict__ b1a,
              const float* __restrict__ W1b, const float* __restrict__ b1b,
              const int* __restrict__ s1_list, const int* __restrict__ cnt,
              const int* __restrict__ e1cnt, const int* __restrict__ e1buf,
              float* __restrict__ hA, float* __restrict__ hB) {
    __shared__ float Wsh[2][DD][DD];
    __shared__ int   sidx[PERCAP];
    __shared__ float snrm[PERCAP];
    __shared__ float aggsh[DD];
    int s1n = cnt[0] < S1CAP ? cnt[0] : S1CAP;
    int i = blockIdx.x;
    if (i >= s1n) return;
    int t = threadIdx.x, st = t >> 5, dd = t & 31;
    {
        float* w0 = &Wsh[0][0][0];
        float* w1 = &Wsh[1][0][0];
        for (int j = t; j < DD * DD; j += 64) { w0[j] = W1a[j]; w1[j] = W1b[j]; }
    }
    int u = s1_list[i];
    float dis_u = rsqrtf((float)deg[u] + 1.0f);
    int ci = e1cnt[i]; if (ci > PERCAP) ci = PERCAP;
    for (int j = t; j < ci; j += 64) {
        int s = e1buf[(size_t)i * PERCAP + j];
        sidx[j] = s;
        snrm[j] = rsqrtf((float)deg[s] + 1.0f) * dis_u;
    }
    __syncthreads();
    float agg = dis_u * dis_u * x[(size_t)u * DD + dd];
#pragma unroll 4
    for (int j = 0; j < ci; ++j)
        agg += snrm[j] * x[(size_t)sidx[j] * DD + dd];
    if (t < DD) aggsh[dd] = agg;
    __syncthreads();
    float y = st ? b1b[dd] : b1a[dd];
#pragma unroll
    for (int k = 0; k < DD; ++k) y += aggsh[k] * Wsh[st][k][dd];
    y = fmaxf(y, 0.f);
    (st ? hB : hA)[(size_t)i * DD + dd] = y;
}

__global__ __launch_bounds__(128)
void k_layer2(const int* __restrict__ deg,
              const float* __restrict__ W2a, const float* __restrict__ b2a,
              const float* __restrict__ W2b, const float* __restrict__ b2b,
              const int* __restrict__ op1p, const int* __restrict__ op2p,
              const int* __restrict__ nidx, const int* __restrict__ cnt,
              const int* __restrict__ e2_src, const int* __restrict__ e2_w,
              const float* __restrict__ hA, const float* __restrict__ hB,
              float* __restrict__ out) {
    __shared__ float Wsh[2][DD][DD];
    __shared__ int   prow[PERCAP];
    __shared__ int   pw[PERCAP];
    __shared__ float pnrm[PERCAP];
    __shared__ float aggsh[2][2][DD];
    __shared__ float ysh[2][2][DD];
    int t = threadIdx.x;
    int st = t >> 6, w = (t >> 5) & 1, dd = t & 31;
    {
        float* w0 = &Wsh[0][0][0];
        float* w1 = &Wsh[1][0][0];
        for (int j = t; j < DD * DD; j += 128) { w0[j] = W2a[j]; w1[j] = W2b[j]; }
    }
    int o1 = op1p[0], o2 = op2p[0];
    int v = w ? o2 : o1;
    float dis_v = rsqrtf((float)deg[v] + 1.0f);
    const float* h = st ? hB : hA;
    int rv = nidx[v] - 1; if (rv < 0) rv = 0;
    float agg = dis_v * dis_v * h[(size_t)rv * DD + dd];
    int c2 = cnt[2] < E2CAP ? cnt[2] : E2CAP;
    for (int j0 = 0; j0 < c2; j0 += PERCAP) {
        int jn = c2 - j0; if (jn > PERCAP) jn = PERCAP;
        __syncthreads();
        if (t < jn) {
            int s = e2_src[j0 + t];
            prow[t] = nidx[s] - 1;
            pw[t]   = e2_w[j0 + t];
            pnrm[t] = rsqrtf((float)deg[s] + 1.0f);
        }
        __syncthreads();
#pragma unroll 4
        for (int j = 0; j < jn; ++j) {
            if (pw[j] == w && prow[j] >= 0)
                agg += (pnrm[j] * dis_v) * h[(size_t)prow[j] * DD + dd];
        }
    }
    aggsh[w][st][dd] = agg;
    __syncthreads();
    float y = st ? b2b[dd] : b2a[dd];
#pragma unroll
    for (int k = 0; k < DD; ++k) y += aggsh[w][st][k] * Wsh[st][k][dd];
    ysh[st][w][dd] = y;
    __syncthreads();
    if (t < 2) {
        float sum = 0.f;
        for (int k = 0; k < DD; ++k) sum += ysh[t][0][k] * ysh[t][1][k];
        out[t] = sum;
    }
}

extern "C" void kernel_launch(void* const* d_in, const int* in_sizes, int n_in,
                              void* d_out, int out_size, void* d_ws, size_t ws_size,
                              hipStream_t stream) {
    const float* x   = (const float*)d_in[0];
    const int*   ei  = (const int*)d_in[1];
    const float* W1a = (const float*)d_in[2];
    const float* b1a = (const float*)d_in[3];
    const float* W2a = (const float*)d_in[4];
    const float* b2a = (const float*)d_in[5];
    const float* W1b = (const float*)d_in[6];
    const float* b1b = (const float*)d_in[7];
    const float* W2b = (const float*)d_in[8];
    const float* b2b = (const float*)d_in[9];
    const int* op1 = (const int*)d_in[10];
    const int* op2 = (const int*)d_in[11];
    int N = in_sizes[0] / DD;
    int E = in_sizes[1] / 2;

    Params P;
    P.x = x; P.ei = ei; P.E = E; P.N = N;
    P.W1a = W1a; P.b1a = b1a; P.W2a = W2a; P.b2a = b2a;
    P.W1b = W1b; P.b1b = b1b; P.W2b = W2b; P.b2b = b2b;
    P.op1p = op1; P.op2p = op2;
    P.ws = (char*)d_ws; P.out = (float*)d_out;

    void* args[] = { &P };
    hipError_t err = hipLaunchCooperativeKernel((const void*)k_fused,
                                                dim3(GRID), dim3(TPB),
                                                args, 0, stream);
    if (err == hipSuccess) return;

    // Fallback: proven round-8 multi-kernel path (deterministic across calls —
    // the cooperative launch either always succeeds or always fails).
    char* p = (char*)d_ws;
    int* cnt   = (int*)p;            p += 64;
    int* e1cnt = (int*)p;            p += S1CAP * 4;
    int* deg   = (int*)p;            p += (size_t)N * 4;
    int* nidx  = (int*)p;            p += (size_t)N * 4;
    unsigned char* need = (unsigned char*)p;
    size_t needpad = ((size_t)N + 15) & ~(size_t)15;
    p += needpad;
    size_t zbytes = 64 + S1CAP * 4 + (size_t)N * 8 + needpad;
    int* s1_list = (int*)p;          p += S1CAP * 4;
    int* e1buf   = (int*)p;          p += (size_t)S1CAP * PERCAP * 4;
    int* e2_src  = (int*)p;          p += E2CAP * 4;
    int* e2_w    = (int*)p;          p += E2CAP * 4;
    float* hA    = (float*)p;        p += (size_t)S1CAP * DD * 4;
    float* hB    = (float*)p;        p += (size_t)S1CAP * DD * 4;

    hipMemsetAsync(d_ws, 0, zbytes, stream);
    int nb4 = (int)(((size_t)E / 4 + 256) / 256);
    k_scan1<<<nb4, 256, 0, stream>>>(ei, E, op1, op2, nidx, s1_list, e2_src, e2_w, cnt, need);
    k_scan2<<<nb4, 256, 0, stream>>>(ei, E, nidx, e1cnt, e1buf, need);
    k_scan3<<<nb4, 256, 0, stream>>>(ei, E, need, deg);
    k_layer1<<<S1CAP, 64, 0, stream>>>(x, deg, W1a, b1a, W1b, b1b,
                                       s1_list, cnt, e1cnt, e1buf, hA, hB);
    k_layer2<<<1, 128, 0, stream>>>(deg, W2a, b2a, W2b, b2b, op1, op2,
                                    nidx, cnt, e2_src, e2_w, hA, hB,
                                    (float*)d_out);
}

// Round 12
// 128.455 us; speedup vs baseline: 3.3470x; 3.3470x over previous
//
#include <hip/hip_runtime.h>
#include <hip/hip_bf16.h>

#define DD 32
#define S1CAP 256
#define PERCAP 128      // per-S1-node in-edge cap (in-degree ~Poisson(16))
#define E2CAP 1024

// Insert node u into the S1 set (dedup via nidx CAS).
// nidx[u]: 0 = absent, -1 = claimed/overflow, >0 = index+1 into s1_list.
__device__ __forceinline__ void s1_insert(int u, int* nidx, int* s1_list, int* cnt) {
    int old = atomicCAS(&nidx[u], 0, -1);
    if (old == 0) {
        int pos = atomicAdd(&cnt[0], 1);
        if (pos < S1CAP) { s1_list[pos] = u; nidx[u] = pos + 1; }
    }
}

// Pass 1: find in-edges of op1/op2 (-> e2 list) and their sources (-> S1).
// 8 edges/thread via 2x int4 on the dst column.
__global__ void k_scan1(const int* __restrict__ ei, int E,
                        const int* __restrict__ op1p, const int* __restrict__ op2p,
                        int* __restrict__ nidx, int* __restrict__ s1_list,
                        int* __restrict__ e2_src, int* __restrict__ e2_w,
                        int* __restrict__ cnt) {
    int tid = blockIdx.x * blockDim.x + threadIdx.x;
    int o1 = op1p[0], o2 = op2p[0];
    if (tid == 0) {
        s1_insert(o1, nidx, s1_list, cnt);
        s1_insert(o2, nidx, s1_list, cnt);
    }
    const int* eid = ei + (size_t)E;
    int nchunk = E >> 3;
    if (tid < nchunk) {
        int base = tid * 8;
        int4 a = *reinterpret_cast<const int4*>(eid + base);
        int4 b = *reinterpret_cast<const int4*>(eid + base + 4);
        int dv[8] = {a.x, a.y, a.z, a.w, b.x, b.y, b.z, b.w};
#pragma unroll
        for (int k = 0; k < 8; ++k) {
            int d = dv[k];
            if (d == o1 || d == o2) {
                int s = ei[base + k];
                s1_insert(s, nidx, s1_list, cnt);
                int q = atomicAdd(&cnt[2], 1);
                if (q < E2CAP) { e2_src[q] = s; e2_w[q] = (d == o2); }
            }
        }
    } else if (tid == nchunk) {             // tail (E % 8 edges)
        for (int e = nchunk * 8; e < E; ++e) {
            int d = eid[e];
            if (d == o1 || d == o2) {
                int s = ei[e];
                s1_insert(s, nidx, s1_list, cnt);
                int q = atomicAdd(&cnt[2], 1);
                if (q < E2CAP) { e2_src[q] = s; e2_w[q] = (d == o2); }
            }
        }
    }
}

// Pass 2: bucket in-edges of S1 into per-node CSR-lite slots. e1cnt[i] ends up
// holding the EXACT in-degree of S1 node i (counts past PERCAP too) — this is
// the degree source for all S1 nodes (replaces deg[] for them). Sources are
// marked in need[] for pass 3.
__global__ void k_scan2(const int* __restrict__ ei, int E,
                        const int* __restrict__ nidx,
                        int* __restrict__ e1cnt, int* __restrict__ e1buf,
                        unsigned char* __restrict__ need) {
    int tid = blockIdx.x * blockDim.x + threadIdx.x;
    const int* eid = ei + (size_t)E;
    int nchunk = E >> 3;
    if (tid < nchunk) {
        int base = tid * 8;
        int4 a = *reinterpret_cast<const int4*>(eid + base);
        int4 b = *reinterpret_cast<const int4*>(eid + base + 4);
        int dv[8] = {a.x, a.y, a.z, a.w, b.x, b.y, b.z, b.w};
#pragma unroll
        for (int k = 0; k < 8; ++k) {
            int ix = nidx[dv[k]];
            if (ix > 0) {
                int s = ei[base + k];
                int slot = atomicAdd(&e1cnt[ix - 1], 1);
                if (slot < PERCAP) e1buf[(size_t)(ix - 1) * PERCAP + slot] = s;
                need[s] = 1;
            }
        }
    } else if (tid == nchunk) {
        for (int e = nchunk * 8; e < E; ++e) {
            int ix = nidx[eid[e]];
            if (ix > 0) {
                int s = ei[e];
                int slot = atomicAdd(&e1cnt[ix - 1], 1);
                if (slot < PERCAP) e1buf[(size_t)(ix - 1) * PERCAP + slot] = s;
                need[s] = 1;
            }
        }
    }
}

// Pass 3: in-degree counting ONLY for e1 sources (~550 of 100k nodes).
__global__ void k_scan3(const int* __restrict__ ei, int E,
                        const unsigned char* __restrict__ need,
                        int* __restrict__ deg) {
    int tid = blockIdx.x * blockDim.x + threadIdx.x;
    const int* eid = ei + (size_t)E;
    int nchunk = E >> 3;
    if (tid < nchunk) {
        int base = tid * 8;
        int4 a = *reinterpret_cast<const int4*>(eid + base);
        int4 b = *reinterpret_cast<const int4*>(eid + base + 4);
        int dv[8] = {a.x, a.y, a.z, a.w, b.x, b.y, b.z, b.w};
#pragma unroll
        for (int k = 0; k < 8; ++k) { int d = dv[k]; if (need[d]) atomicAdd(&deg[d], 1); }
    } else if (tid == nchunk) {
        for (int e = nchunk * 8; e < E; ++e) {
            int d = eid[e]; if (need[d]) atomicAdd(&deg[d], 1);
        }
    }
}

// Layer 1 (both stacks) at S1 nodes, CSR-lite: block i reads only its own
// ~16 in-edges. dis_u comes from e1cnt[i] (exact in-degree); source degrees
// from deg[] (scan3). 64 threads: st = t>>5, dd = t&31.
__global__ __launch_bounds__(64)
void k_layer1(const float* __restrict__ x, const int* __restrict__ deg,
              const float* __restrict__ W1a, const float* __restrict__ b1a,
              const float* __restrict__ W1b, const float* __restrict__ b1b,
              const int* __restrict__ s1_list, const int* __restrict__ cnt,
              const int* __restrict__ e1cnt, const int* __restrict__ e1buf,
              float* __restrict__ hA, float* __restrict__ hB) {
    __shared__ float Wsh[2][DD][DD];
    __shared__ int   sidx[PERCAP];
    __shared__ float snrm[PERCAP];
    __shared__ float aggsh[DD];
    int s1n = cnt[0] < S1CAP ? cnt[0] : S1CAP;
    int i = blockIdx.x;
    if (i >= s1n) return;
    int t = threadIdx.x, st = t >> 5, dd = t & 31;
    {
        float* w0 = &Wsh[0][0][0];
        float* w1 = &Wsh[1][0][0];
        for (int j = t; j < DD * DD; j += 64) { w0[j] = W1a[j]; w1[j] = W1b[j]; }
    }
    int u = s1_list[i];
    int du = e1cnt[i];                          // exact in-degree of u
    float dis_u = rsqrtf((float)du + 1.0f);
    int ci = du < PERCAP ? du : PERCAP;
    for (int j = t; j < ci; j += 64) {          // parallel prep (deg gathers)
        int s = e1buf[(size_t)i * PERCAP + j];
        sidx[j] = s;
        snrm[j] = rsqrtf((float)deg[s] + 1.0f) * dis_u;   // dis_u block-uniform
    }
    __syncthreads();
    float agg = dis_u * dis_u * x[(size_t)u * DD + dd];   // self-loop
#pragma unroll 4
    for (int j = 0; j < ci; ++j)
        agg += snrm[j] * x[(size_t)sidx[j] * DD + dd];
    if (t < DD) aggsh[dd] = agg;                // halves computed identical agg
    __syncthreads();
    float y = st ? b1b[dd] : b1a[dd];
#pragma unroll
    for (int k = 0; k < DD; ++k) y += aggsh[k] * Wsh[st][k][dd];
    y = fmaxf(y, 0.f);                          // ReLU
    (st ? hB : hA)[(size_t)i * DD + dd] = y;
}

// Layer 2 at op1/op2 + final dots. ALL degrees come from e1cnt (v=op1/op2 and
// every e2 source are S1 members by construction) — no deg[] reads here.
// pnrm holds ONLY the source factor; consumer applies its own dis_v (r7 bug).
// 128 threads: st=t>>6, w=(t>>5)&1, dd=t&31.
__global__ __launch_bounds__(128)
void k_layer2(const float* __restrict__ W2a, const float* __restrict__ b2a,
              const float* __restrict__ W2b, const float* __restrict__ b2b,
              const int* __restrict__ op1p, const int* __restrict__ op2p,
              const int* __restrict__ nidx, const int* __restrict__ cnt,
              const int* __restrict__ e1cnt,
              const int* __restrict__ e2_src, const int* __restrict__ e2_w,
              const float* __restrict__ hA, const float* __restrict__ hB,
              float* __restrict__ out) {
    __shared__ float Wsh[2][DD][DD];
    __shared__ int   prow[PERCAP];
    __shared__ int   pw[PERCAP];
    __shared__ float pnrm[PERCAP];
    __shared__ float aggsh[2][2][DD];   // [w][st][dd]
    __shared__ float ysh[2][2][DD];     // [st][w][dd]
    int t = threadIdx.x;
    int st = t >> 6, w = (t >> 5) & 1, dd = t & 31;
    {
        float* w0 = &Wsh[0][0][0];
        float* w1 = &Wsh[1][0][0];
        for (int j = t; j < DD * DD; j += 128) { w0[j] = W2a[j]; w1[j] = W2b[j]; }
    }
    int o1 = op1p[0], o2 = op2p[0];
    int v = w ? o2 : o1;
    int rv = nidx[v] - 1; if (rv < 0) rv = 0;
    float dis_v = rsqrtf((float)e1cnt[rv] + 1.0f);
    const float* h = st ? hB : hA;      // st is wave-uniform
    float agg = dis_v * dis_v * h[(size_t)rv * DD + dd];   // self-loop
    int c2 = cnt[2] < E2CAP ? cnt[2] : E2CAP;
    for (int j0 = 0; j0 < c2; j0 += PERCAP) {
        int jn = c2 - j0; if (jn > PERCAP) jn = PERCAP;
        __syncthreads();
        if (t < jn) {                    // parallel prep (nidx/e1cnt gathers)
            int s = e2_src[j0 + t];
            int r = nidx[s] - 1;
            prow[t] = r;
            pw[t]   = e2_w[j0 + t];
            pnrm[t] = (r >= 0) ? rsqrtf((float)e1cnt[r] + 1.0f) : 0.f;
        }
        __syncthreads();
#pragma unroll 4
        for (int j = 0; j < jn; ++j) {
            if (pw[j] == w && prow[j] >= 0)
                agg += (pnrm[j] * dis_v) * h[(size_t)prow[j] * DD + dd];
        }
    }
    aggsh[w][st][dd] = agg;
    __syncthreads();
    float y = st ? b2b[dd] : b2a[dd];
#pragma unroll
    for (int k = 0; k < DD; ++k) y += aggsh[w][st][k] * Wsh[st][k][dd];
    ysh[st][w][dd] = y;
    __syncthreads();
    if (t < 2) {
        float sum = 0.f;
        for (int k = 0; k < DD; ++k) sum += ysh[t][0][k] * ysh[t][1][k];
        out[t] = sum;                   // f32 output: out[0]=l1, out[1]=l2
    }
}

extern "C" void kernel_launch(void* const* d_in, const int* in_sizes, int n_in,
                              void* d_out, int out_size, void* d_ws, size_t ws_size,
                              hipStream_t stream) {
    const float* x   = (const float*)d_in[0];
    const int*   ei  = (const int*)d_in[1];
    const float* W1a = (const float*)d_in[2];
    const float* b1a = (const float*)d_in[3];
    const float* W2a = (const float*)d_in[4];
    const float* b2a = (const float*)d_in[5];
    const float* W1b = (const float*)d_in[6];
    const float* b1b = (const float*)d_in[7];
    const float* W2b = (const float*)d_in[8];
    const float* b2b = (const float*)d_in[9];
    const int* op1 = (const int*)d_in[10];
    const int* op2 = (const int*)d_in[11];
    int N = in_sizes[0] / DD;
    int E = in_sizes[1] / 2;

    // Workspace: [cnt | e1cnt | deg | nidx | need] is one zero-memset region.
    char* p = (char*)d_ws;
    int* cnt   = (int*)p;            p += 64;
    int* e1cnt = (int*)p;            p += S1CAP * 4;
    int* deg   = (int*)p;            p += (size_t)N * 4;
    int* nidx  = (int*)p;            p += (size_t)N * 4;
    unsigned char* need = (unsigned char*)p;
    size_t needpad = ((size_t)N + 15) & ~(size_t)15;
    p += needpad;
    size_t zbytes = 64 + S1CAP * 4 + (size_t)N * 8 + needpad;
    int* s1_list = (int*)p;          p += S1CAP * 4;
    int* e1buf   = (int*)p;          p += (size_t)S1CAP * PERCAP * 4;
    int* e2_src  = (int*)p;          p += E2CAP * 4;
    int* e2_w    = (int*)p;          p += E2CAP * 4;
    float* hA    = (float*)p;        p += (size_t)S1CAP * DD * 4;
    float* hB    = (float*)p;        p += (size_t)S1CAP * DD * 4;

    hipMemsetAsync(d_ws, 0, zbytes, stream);

    // 8 edges/thread; +1 thread for the tail
    int nthreads = (E >> 3) + 1;
    int nb = (nthreads + 255) / 256;
    k_scan1<<<nb, 256, 0, stream>>>(ei, E, op1, op2, nidx, s1_list, e2_src, e2_w, cnt);
    k_scan2<<<nb, 256, 0, stream>>>(ei, E, nidx, e1cnt, e1buf, need);
    k_scan3<<<nb, 256, 0, stream>>>(ei, E, need, deg);
    k_layer1<<<S1CAP, 64, 0, stream>>>(x, deg, W1a, b1a, W1b, b1b,
                                       s1_list, cnt, e1cnt, e1buf, hA, hB);
    k_layer2<<<1, 128, 0, stream>>>(W2a, b2a, W2b, b2b, op1, op2,
                                    nidx, cnt, e1cnt, e2_src, e2_w, hA, hB,
                                    (float*)d_out);
}